// Round 1
// baseline (371.332 us; speedup 1.0000x reference)
//
#include <hip/hip_runtime.h>

#define N_NODES 50000
#define N_EDGES 800000
#define D 128
#define NCHUNK 196   // ceil(50000/256)

// ---------- graph build ----------

__global__ void k_zero(int* __restrict__ p, int n) {
    int i = blockIdx.x * blockDim.x + threadIdx.x;
    if (i < n) p[i] = 0;
}

__global__ void k_hist(const int* __restrict__ ei, int* __restrict__ cnt) {
    int e = blockIdx.x * blockDim.x + threadIdx.x;
    if (e < N_EDGES) atomicAdd(&cnt[ei[N_EDGES + e]], 1);
}

// block-wise inclusive scan (Hillis-Steele) helper pattern used inline below

__global__ void k_scan1(const int* __restrict__ cnt, int* __restrict__ chunkscan,
                        int* __restrict__ csum) {
    __shared__ int sd[256];
    int t = threadIdx.x;
    int i = blockIdx.x * 256 + t;
    int v = (i < N_NODES) ? cnt[i] : 0;
    sd[t] = v;
    __syncthreads();
    for (int off = 1; off < 256; off <<= 1) {
        int u = (t >= off) ? sd[t - off] : 0;
        __syncthreads();
        sd[t] += u;
        __syncthreads();
    }
    if (i < N_NODES) chunkscan[i] = sd[t] - v;   // exclusive within chunk
    if (t == 255) csum[blockIdx.x] = sd[255];    // chunk total
}

__global__ void k_scan2(int* __restrict__ csum, int nb) {
    __shared__ int sd[256];
    int t = threadIdx.x;
    int v = (t < nb) ? csum[t] : 0;
    sd[t] = v;
    __syncthreads();
    for (int off = 1; off < 256; off <<= 1) {
        int u = (t >= off) ? sd[t - off] : 0;
        __syncthreads();
        sd[t] += u;
        __syncthreads();
    }
    if (t < nb) csum[t] = sd[t] - v;             // exclusive scan of chunk totals
}

__global__ void k_finalize(const int* __restrict__ cnt, const int* __restrict__ chunkscan,
                           const int* __restrict__ csum, int* __restrict__ rowptr,
                           int* __restrict__ cursor, float* __restrict__ dinv) {
    int i = blockIdx.x * 256 + threadIdx.x;
    if (i < N_NODES) {
        int r = chunkscan[i] + csum[i >> 8];
        rowptr[i] = r;
        cursor[i] = r;
        dinv[i] = rsqrtf((float)cnt[i] + 1.0f);  // +1 self-loop
    }
    if (i == 0) rowptr[N_NODES] = N_EDGES;
}

__global__ void k_scatter(const int* __restrict__ ei, int* __restrict__ cursor,
                          int* __restrict__ esrc) {
    int e = blockIdx.x * blockDim.x + threadIdx.x;
    if (e < N_EDGES) {
        int s  = ei[e];
        int dt = ei[N_EDGES + e];
        int pos = atomicAdd(&cursor[dt], 1);
        esrc[pos] = s;
    }
}

// ---------- dense transform: H = X @ W  (f32 vector ALU, W staged in LDS) ----------
// grid = 6250 blocks x 256 threads, 8 rows/block, thread = (row-in-block, 4-col group)

__global__ __launch_bounds__(256) void k_gemm(const float* __restrict__ X,
                                              const float* __restrict__ W,
                                              float* __restrict__ H) {
    __shared__ float4 Ws[128 * 32];   // 64 KiB: W[k][j] as float4 over j
    __shared__ float  Xs[8][128];     // 4 KiB
    const float4* Wv = (const float4*)W;
    for (int i = threadIdx.x; i < 128 * 32; i += 256) Ws[i] = Wv[i];

    int base = blockIdx.x * 8;
    ((float4*)Xs)[threadIdx.x] = ((const float4*)(X + (size_t)base * D))[threadIdx.x];
    __syncthreads();

    int r8 = threadIdx.x >> 5;   // 0..7 row within block
    int c4 = threadIdx.x & 31;   // 0..31 float4-column
    float4 acc = make_float4(0.f, 0.f, 0.f, 0.f);
#pragma unroll 16
    for (int k = 0; k < 128; ++k) {
        float  xv = Xs[r8][k];
        float4 w  = Ws[k * 32 + c4];
        acc.x = fmaf(xv, w.x, acc.x);
        acc.y = fmaf(xv, w.y, acc.y);
        acc.z = fmaf(xv, w.z, acc.z);
        acc.w = fmaf(xv, w.w, acc.w);
    }
    ((float4*)(H + (size_t)(base + r8) * D))[c4] = acc;
}

// ---------- aggregation: out[n] = dinv[n]*(h[n]*dinv[n] + sum_e h[src]*dinv[src]) + b ----------
// 32 lanes per node (float4 per lane), 8 nodes per 256-thread block, CSR gather, no atomics.

template <int RELU>
__global__ __launch_bounds__(256) void k_agg(const float* __restrict__ H,
                                             const int* __restrict__ esrc,
                                             const int* __restrict__ rowptr,
                                             const float* __restrict__ dinv,
                                             const float* __restrict__ bias,
                                             float* __restrict__ OUT) {
    int node = blockIdx.x * 8 + (threadIdx.x >> 5);
    int c4   = threadIdx.x & 31;
    const float4* Hv = (const float4*)H;

    float di = dinv[node];
    float4 h0 = Hv[(size_t)node * 32 + c4];
    float4 acc;
    acc.x = h0.x * di;
    acc.y = h0.y * di;
    acc.z = h0.z * di;
    acc.w = h0.w * di;

    int s = rowptr[node], e = rowptr[node + 1];
    for (int i = s; i < e; ++i) {
        int   src = esrc[i];
        float ds  = dinv[src];
        float4 hv = Hv[(size_t)src * 32 + c4];
        acc.x = fmaf(hv.x, ds, acc.x);
        acc.y = fmaf(hv.y, ds, acc.y);
        acc.z = fmaf(hv.z, ds, acc.z);
        acc.w = fmaf(hv.w, ds, acc.w);
    }

    float4 b = ((const float4*)bias)[c4];
    float4 r;
    r.x = fmaf(acc.x, di, b.x);
    r.y = fmaf(acc.y, di, b.y);
    r.z = fmaf(acc.z, di, b.z);
    r.w = fmaf(acc.w, di, b.w);
    if (RELU) {
        r.x = fmaxf(r.x, 0.f);
        r.y = fmaxf(r.y, 0.f);
        r.z = fmaxf(r.z, 0.f);
        r.w = fmaxf(r.w, 0.f);
    }
    ((float4*)OUT)[(size_t)node * 32 + c4] = r;
}

// ---------- launch ----------

extern "C" void kernel_launch(void* const* d_in, const int* in_sizes, int n_in,
                              void* d_out, int out_size, void* d_ws, size_t ws_size,
                              hipStream_t stream) {
    const float* x  = (const float*)d_in[0];
    const int*   ei = (const int*)d_in[1];
    const float* W1 = (const float*)d_in[2];
    const float* b1 = (const float*)d_in[3];
    const float* W2 = (const float*)d_in[4];
    const float* b2 = (const float*)d_in[5];
    float* out = (float*)d_out;

    // ws layout (elements, 4B each; chunks padded to keep 16B alignment)
    int*   cnt       = (int*)d_ws;               // 50000
    int*   chunkscan = cnt + 50048;              // 50000
    int*   csum      = chunkscan + 50048;        // 256
    int*   rowptr    = csum + 256;               // 50001
    int*   cursor    = rowptr + 50048;           // 50000
    float* dinv      = (float*)(cursor + 50048); // 50000
    int*   esrc      = (int*)(dinv + 50048);     // 800000
    float* h         = (float*)(esrc + 800000);  // 6,400,000
    float* agg       = h + 6400000;              // 6,400,000

    const int TB = 256;
    const int gbN = (N_NODES + TB - 1) / TB;     // 196
    const int gbE = (N_EDGES + TB - 1) / TB;     // 3125

    // graph build (shared by both layers)
    k_zero<<<gbN, TB, 0, stream>>>(cnt, N_NODES);
    k_hist<<<gbE, TB, 0, stream>>>(ei, cnt);
    k_scan1<<<NCHUNK, TB, 0, stream>>>(cnt, chunkscan, csum);
    k_scan2<<<1, TB, 0, stream>>>(csum, NCHUNK);
    k_finalize<<<gbN, TB, 0, stream>>>(cnt, chunkscan, csum, rowptr, cursor, dinv);
    k_scatter<<<gbE, TB, 0, stream>>>(ei, cursor, esrc);

    // layer 1
    k_gemm<<<N_NODES / 8, TB, 0, stream>>>(x, W1, h);
    k_agg<1><<<N_NODES / 8, TB, 0, stream>>>(h, esrc, rowptr, dinv, b1, agg);
    // layer 2
    k_gemm<<<N_NODES / 8, TB, 0, stream>>>(agg, W2, h);
    k_agg<0><<<N_NODES / 8, TB, 0, stream>>>(h, esrc, rowptr, dinv, b2, out);
}

// Round 2
// 285.963 us; speedup vs baseline: 1.2985x; 1.2985x over previous
//
#include <hip/hip_runtime.h>

#define N_NODES 50000
#define N_EDGES 800000
#define D 128
#define NCHUNK 196   // ceil(50000/256)

// ---------- graph build ----------

__global__ void k_zero(int* __restrict__ p, int n) {
    int i = blockIdx.x * blockDim.x + threadIdx.x;
    if (i < n) p[i] = 0;
}

__global__ void k_hist(const int* __restrict__ ei, int* __restrict__ cnt) {
    int e = blockIdx.x * blockDim.x + threadIdx.x;
    if (e < N_EDGES) atomicAdd(&cnt[ei[N_EDGES + e]], 1);
}

__global__ void k_scan1(const int* __restrict__ cnt, int* __restrict__ chunkscan,
                        int* __restrict__ csum) {
    __shared__ int sd[256];
    int t = threadIdx.x;
    int i = blockIdx.x * 256 + t;
    int v = (i < N_NODES) ? cnt[i] : 0;
    sd[t] = v;
    __syncthreads();
    for (int off = 1; off < 256; off <<= 1) {
        int u = (t >= off) ? sd[t - off] : 0;
        __syncthreads();
        sd[t] += u;
        __syncthreads();
    }
    if (i < N_NODES) chunkscan[i] = sd[t] - v;   // exclusive within chunk
    if (t == 255) csum[blockIdx.x] = sd[255];    // chunk total
}

__global__ void k_scan2(int* __restrict__ csum, int nb) {
    __shared__ int sd[256];
    int t = threadIdx.x;
    int v = (t < nb) ? csum[t] : 0;
    sd[t] = v;
    __syncthreads();
    for (int off = 1; off < 256; off <<= 1) {
        int u = (t >= off) ? sd[t - off] : 0;
        __syncthreads();
        sd[t] += u;
        __syncthreads();
    }
    if (t < nb) csum[t] = sd[t] - v;             // exclusive scan of chunk totals
}

__global__ void k_finalize(const int* __restrict__ cnt, const int* __restrict__ chunkscan,
                           const int* __restrict__ csum, int* __restrict__ rowptr,
                           int* __restrict__ cursor, float* __restrict__ dinv) {
    int i = blockIdx.x * 256 + threadIdx.x;
    if (i < N_NODES) {
        int r = chunkscan[i] + csum[i >> 8];
        rowptr[i] = r;
        cursor[i] = r;
        dinv[i] = rsqrtf((float)cnt[i] + 1.0f);  // +1 self-loop
    }
    if (i == 0) rowptr[N_NODES] = N_EDGES;
}

__global__ void k_scatter(const int* __restrict__ ei, int* __restrict__ cursor,
                          int* __restrict__ esrc) {
    int e = blockIdx.x * blockDim.x + threadIdx.x;
    if (e < N_EDGES) {
        int s  = ei[e];
        int dt = ei[N_EDGES + e];
        int pos = atomicAdd(&cursor[dt], 1);
        esrc[pos] = s;
    }
}

// ---------- dense transform: H = X @ W ----------
// 64 rows/block, 256 threads. Thread = (rowgroup rg 0..7, float4-col c4 0..31),
// T_M=8 register tile: acc[8] float4 (8 rows x 4 cols).
// LDS: Xt transposed [k][row] 32KB + W half-tile [64][128] 32KB = 64KB -> 2 blocks/CU.
// Per k-step/thread: 3x ds_read_b128 (48B) for 64 FLOP -> VALU-bound.

__global__ __launch_bounds__(256) void k_gemm(const float* __restrict__ X,
                                              const float* __restrict__ W,
                                              float* __restrict__ H) {
    __shared__ float4 Ws[64 * 32];   // 32 KiB: half of W, [kk][j4]
    __shared__ float  Xt[128][64];   // 32 KiB: transposed X tile [k][row]

    const int tid  = threadIdx.x;
    const int base = blockIdx.x * 64;

    // stage X transposed: thread handles row r = tid>>2, float4-chunks (tid&3)+4j.
    // LDS bank = row%32 (64-float rows) -> 4 lanes/bank on writes (4-way, cheap, one-time).
    {
        int r  = tid >> 2;
        int gr = base + r;
        if (gr >= N_NODES) gr = N_NODES - 1;      // clamp; tail rows never stored
        const float4* Xr = (const float4*)(X + (size_t)gr * D);
#pragma unroll
        for (int j = 0; j < 8; ++j) {
            int c = (tid & 3) + 4 * j;
            float4 v = Xr[c];
            int k0 = c * 4;
            Xt[k0 + 0][r] = v.x;
            Xt[k0 + 1][r] = v.y;
            Xt[k0 + 2][r] = v.z;
            Xt[k0 + 3][r] = v.w;
        }
    }

    const int rg = tid >> 5;
    const int c4 = tid & 31;
    float4 acc[8];
#pragma unroll
    for (int j = 0; j < 8; ++j) acc[j] = make_float4(0.f, 0.f, 0.f, 0.f);

    const float4* Wv = (const float4*)W;
#pragma unroll
    for (int h = 0; h < 2; ++h) {
        __syncthreads();             // Xt ready (h=0) / prev W half consumed (h=1)
        for (int i = tid; i < 64 * 32; i += 256) Ws[i] = Wv[h * 2048 + i];
        __syncthreads();
#pragma unroll 4
        for (int kk = 0; kk < 64; ++kk) {
            float4 w  = Ws[kk * 32 + c4];
            float4 xa = *(const float4*)&Xt[h * 64 + kk][rg * 8];
            float4 xb = *(const float4*)&Xt[h * 64 + kk][rg * 8 + 4];
            float xv[8] = {xa.x, xa.y, xa.z, xa.w, xb.x, xb.y, xb.z, xb.w};
#pragma unroll
            for (int j = 0; j < 8; ++j) {
                acc[j].x = fmaf(xv[j], w.x, acc[j].x);
                acc[j].y = fmaf(xv[j], w.y, acc[j].y);
                acc[j].z = fmaf(xv[j], w.z, acc[j].z);
                acc[j].w = fmaf(xv[j], w.w, acc[j].w);
            }
        }
    }

#pragma unroll
    for (int j = 0; j < 8; ++j) {
        int gr = base + rg * 8 + j;
        if (gr < N_NODES)
            ((float4*)(H + (size_t)gr * D))[c4] = acc[j];
    }
}

// ---------- aggregation: out[n] = dinv[n]*(h[n]*dinv[n] + sum_e h[src]*dinv[src]) + b ----------
// 32 lanes per node (float4/lane), 8 nodes per block, CSR gather, no atomics.
// Edge loop unrolled 2x so two (esrc -> h[src]) gather chains are in flight.

template <int RELU>
__global__ __launch_bounds__(256) void k_agg(const float* __restrict__ H,
                                             const int* __restrict__ esrc,
                                             const int* __restrict__ rowptr,
                                             const float* __restrict__ dinv,
                                             const float* __restrict__ bias,
                                             float* __restrict__ OUT) {
    int node = blockIdx.x * 8 + (threadIdx.x >> 5);
    int c4   = threadIdx.x & 31;
    const float4* Hv = (const float4*)H;

    float di = dinv[node];
    float4 h0 = Hv[(size_t)node * 32 + c4];
    float4 acc;
    acc.x = h0.x * di;
    acc.y = h0.y * di;
    acc.z = h0.z * di;
    acc.w = h0.w * di;

    int s = rowptr[node], e = rowptr[node + 1];
    int i = s;
    for (; i + 1 < e; i += 2) {
        int   s0 = esrc[i],     s1 = esrc[i + 1];
        float d0 = dinv[s0],    d1 = dinv[s1];
        float4 v0 = Hv[(size_t)s0 * 32 + c4];
        float4 v1 = Hv[(size_t)s1 * 32 + c4];
        acc.x = fmaf(v0.x, d0, acc.x);
        acc.y = fmaf(v0.y, d0, acc.y);
        acc.z = fmaf(v0.z, d0, acc.z);
        acc.w = fmaf(v0.w, d0, acc.w);
        acc.x = fmaf(v1.x, d1, acc.x);
        acc.y = fmaf(v1.y, d1, acc.y);
        acc.z = fmaf(v1.z, d1, acc.z);
        acc.w = fmaf(v1.w, d1, acc.w);
    }
    if (i < e) {
        int   s0 = esrc[i];
        float d0 = dinv[s0];
        float4 v0 = Hv[(size_t)s0 * 32 + c4];
        acc.x = fmaf(v0.x, d0, acc.x);
        acc.y = fmaf(v0.y, d0, acc.y);
        acc.z = fmaf(v0.z, d0, acc.z);
        acc.w = fmaf(v0.w, d0, acc.w);
    }

    float4 b = ((const float4*)bias)[c4];
    float4 r;
    r.x = fmaf(acc.x, di, b.x);
    r.y = fmaf(acc.y, di, b.y);
    r.z = fmaf(acc.z, di, b.z);
    r.w = fmaf(acc.w, di, b.w);
    if (RELU) {
        r.x = fmaxf(r.x, 0.f);
        r.y = fmaxf(r.y, 0.f);
        r.z = fmaxf(r.z, 0.f);
        r.w = fmaxf(r.w, 0.f);
    }
    ((float4*)OUT)[(size_t)node * 32 + c4] = r;
}

// ---------- launch ----------

extern "C" void kernel_launch(void* const* d_in, const int* in_sizes, int n_in,
                              void* d_out, int out_size, void* d_ws, size_t ws_size,
                              hipStream_t stream) {
    const float* x  = (const float*)d_in[0];
    const int*   ei = (const int*)d_in[1];
    const float* W1 = (const float*)d_in[2];
    const float* b1 = (const float*)d_in[3];
    const float* W2 = (const float*)d_in[4];
    const float* b2 = (const float*)d_in[5];
    float* out = (float*)d_out;

    // ws layout (elements, 4B each; chunks padded to keep 16B alignment)
    int*   cnt       = (int*)d_ws;               // 50000
    int*   chunkscan = cnt + 50048;              // 50000
    int*   csum      = chunkscan + 50048;        // 256
    int*   rowptr    = csum + 256;               // 50001
    int*   cursor    = rowptr + 50048;           // 50000
    float* dinv      = (float*)(cursor + 50048); // 50000
    int*   esrc      = (int*)(dinv + 50048);     // 800000
    float* h         = (float*)(esrc + 800000);  // 6,400,000
    float* agg       = h + 6400000;              // 6,400,000

    const int TB = 256;
    const int gbN = (N_NODES + TB - 1) / TB;     // 196
    const int gbE = (N_EDGES + TB - 1) / TB;     // 3125
    const int gbG = (N_NODES + 63) / 64;         // 782 gemm blocks

    // graph build (shared by both layers)
    k_zero<<<gbN, TB, 0, stream>>>(cnt, N_NODES);
    k_hist<<<gbE, TB, 0, stream>>>(ei, cnt);
    k_scan1<<<NCHUNK, TB, 0, stream>>>(cnt, chunkscan, csum);
    k_scan2<<<1, TB, 0, stream>>>(csum, NCHUNK);
    k_finalize<<<gbN, TB, 0, stream>>>(cnt, chunkscan, csum, rowptr, cursor, dinv);
    k_scatter<<<gbE, TB, 0, stream>>>(ei, cursor, esrc);

    // layer 1
    k_gemm<<<gbG, TB, 0, stream>>>(x, W1, h);
    k_agg<1><<<N_NODES / 8, TB, 0, stream>>>(h, esrc, rowptr, dinv, b1, agg);
    // layer 2
    k_gemm<<<gbG, TB, 0, stream>>>(agg, W2, h);
    k_agg<0><<<N_NODES / 8, TB, 0, stream>>>(h, esrc, rowptr, dinv, b2, out);
}

// Round 3
// 283.883 us; speedup vs baseline: 1.3080x; 1.0073x over previous
//
#include <hip/hip_runtime.h>

#define N_NODES 50000
#define N_EDGES 800000
#define D 128
#define NCHUNK 196   // ceil(50000/256)

typedef float f32x4 __attribute__((ext_vector_type(4)));

// ---------- graph build ----------

__global__ void k_zero(int* __restrict__ p, int n) {
    int i = blockIdx.x * blockDim.x + threadIdx.x;
    if (i < n) p[i] = 0;
}

__global__ void k_hist(const int* __restrict__ ei, int* __restrict__ cnt) {
    int e = blockIdx.x * blockDim.x + threadIdx.x;
    if (e < N_EDGES) atomicAdd(&cnt[ei[N_EDGES + e]], 1);
}

__global__ void k_scan1(const int* __restrict__ cnt, int* __restrict__ chunkscan,
                        int* __restrict__ csum) {
    __shared__ int sd[256];
    int t = threadIdx.x;
    int i = blockIdx.x * 256 + t;
    int v = (i < N_NODES) ? cnt[i] : 0;
    sd[t] = v;
    __syncthreads();
    for (int off = 1; off < 256; off <<= 1) {
        int u = (t >= off) ? sd[t - off] : 0;
        __syncthreads();
        sd[t] += u;
        __syncthreads();
    }
    if (i < N_NODES) chunkscan[i] = sd[t] - v;   // exclusive within chunk
    if (t == 255) csum[blockIdx.x] = sd[255];    // chunk total
}

__global__ void k_scan2(int* __restrict__ csum, int nb) {
    __shared__ int sd[256];
    int t = threadIdx.x;
    int v = (t < nb) ? csum[t] : 0;
    sd[t] = v;
    __syncthreads();
    for (int off = 1; off < 256; off <<= 1) {
        int u = (t >= off) ? sd[t - off] : 0;
        __syncthreads();
        sd[t] += u;
        __syncthreads();
    }
    if (t < nb) csum[t] = sd[t] - v;             // exclusive scan of chunk totals
}

__global__ void k_finalize(const int* __restrict__ cnt, const int* __restrict__ chunkscan,
                           const int* __restrict__ csum, int* __restrict__ rowptr,
                           int* __restrict__ cursor, float* __restrict__ dinv) {
    int i = blockIdx.x * 256 + threadIdx.x;
    if (i < N_NODES) {
        int r = chunkscan[i] + csum[i >> 8];
        rowptr[i] = r;
        cursor[i] = r;
        dinv[i] = rsqrtf((float)cnt[i] + 1.0f);  // +1 self-loop
    }
    if (i == 0) rowptr[N_NODES] = N_EDGES;
}

__global__ void k_scatter(const int* __restrict__ ei, int* __restrict__ cursor,
                          int* __restrict__ esrc) {
    int e = blockIdx.x * blockDim.x + threadIdx.x;
    if (e < N_EDGES) {
        int s  = ei[e];
        int dt = ei[N_EDGES + e];
        int pos = atomicAdd(&cursor[dt], 1);
        esrc[pos] = s;
    }
}

// ---------- dense transform: H' = (X @ W) * dinv[row] ----------
// 64 rows/block, 256 threads, T_M=8 register tile.
// Epilogue folds the dinv[row] scale so k_agg needs no per-edge dinv gather.

__global__ __launch_bounds__(256) void k_gemm(const float* __restrict__ X,
                                              const float* __restrict__ W,
                                              const float* __restrict__ dinv,
                                              float* __restrict__ H) {
    __shared__ float4 Ws[64 * 32];   // 32 KiB: half of W, [kk][j4]
    __shared__ float  Xt[128][64];   // 32 KiB: transposed X tile [k][row]

    const int tid  = threadIdx.x;
    const int base = blockIdx.x * 64;

    {
        int r  = tid >> 2;
        int gr = base + r;
        if (gr >= N_NODES) gr = N_NODES - 1;      // clamp; tail rows never stored
        const float4* Xr = (const float4*)(X + (size_t)gr * D);
#pragma unroll
        for (int j = 0; j < 8; ++j) {
            int c = (tid & 3) + 4 * j;
            float4 v = Xr[c];
            int k0 = c * 4;
            Xt[k0 + 0][r] = v.x;
            Xt[k0 + 1][r] = v.y;
            Xt[k0 + 2][r] = v.z;
            Xt[k0 + 3][r] = v.w;
        }
    }

    const int rg = tid >> 5;
    const int c4 = tid & 31;
    float4 acc[8];
#pragma unroll
    for (int j = 0; j < 8; ++j) acc[j] = make_float4(0.f, 0.f, 0.f, 0.f);

    const float4* Wv = (const float4*)W;
#pragma unroll
    for (int h = 0; h < 2; ++h) {
        __syncthreads();             // Xt ready (h=0) / prev W half consumed (h=1)
        for (int i = tid; i < 64 * 32; i += 256) Ws[i] = Wv[h * 2048 + i];
        __syncthreads();
#pragma unroll 4
        for (int kk = 0; kk < 64; ++kk) {
            float4 w  = Ws[kk * 32 + c4];
            float4 xa = *(const float4*)&Xt[h * 64 + kk][rg * 8];
            float4 xb = *(const float4*)&Xt[h * 64 + kk][rg * 8 + 4];
            float xv[8] = {xa.x, xa.y, xa.z, xa.w, xb.x, xb.y, xb.z, xb.w};
#pragma unroll
            for (int j = 0; j < 8; ++j) {
                acc[j].x = fmaf(xv[j], w.x, acc[j].x);
                acc[j].y = fmaf(xv[j], w.y, acc[j].y);
                acc[j].z = fmaf(xv[j], w.z, acc[j].z);
                acc[j].w = fmaf(xv[j], w.w, acc[j].w);
            }
        }
    }

#pragma unroll
    for (int j = 0; j < 8; ++j) {
        int gr = base + rg * 8 + j;
        if (gr < N_NODES) {
            float s = dinv[gr];
            float4 r;
            r.x = acc[j].x * s;
            r.y = acc[j].y * s;
            r.z = acc[j].z * s;
            r.w = acc[j].w * s;
            ((float4*)(H + (size_t)gr * D))[c4] = r;
        }
    }
}

// ---------- aggregation: out[n] = dinv[n]*(h'[n] + sum_e h'[src]) + b ----------
// 32 lanes per node (float4/lane), 8 nodes per block, CSR gather, no atomics.
// One coalesced load fetches 32 edge indices per group (lane i holds esrc[off+i]);
// __shfl broadcasts make all gather addresses available immediately -> 4 row
// gathers in flight per unrolled step. Outputs stored nontemporal to keep h' in L2.

template <int RELU>
__global__ __launch_bounds__(256) void k_agg(const float* __restrict__ Hs,
                                             const int* __restrict__ esrc,
                                             const int* __restrict__ rowptr,
                                             const float* __restrict__ dinv,
                                             const float* __restrict__ bias,
                                             float* __restrict__ OUT) {
    int node = blockIdx.x * 8 + (threadIdx.x >> 5);
    int lane = threadIdx.x & 31;
    const f32x4* Hv = (const f32x4*)Hs;

    float di = dinv[node];
    f32x4 acc = Hv[(size_t)node * 32 + lane];     // h'[n] (self-loop term)

    int s = rowptr[node], e = rowptr[node + 1];
    for (int off = s; off < e; off += 32) {
        int n = e - off;
        if (n > 32) n = 32;
        int idx  = off + (lane < n ? lane : n - 1);   // clamp: no OOB reads
        int eidx = __builtin_nontemporal_load(&esrc[idx]);
        int j = 0;
        for (; j + 3 < n; j += 4) {
            int s0 = __shfl(eidx, j, 32);
            int s1 = __shfl(eidx, j + 1, 32);
            int s2 = __shfl(eidx, j + 2, 32);
            int s3 = __shfl(eidx, j + 3, 32);
            f32x4 v0 = Hv[(size_t)s0 * 32 + lane];
            f32x4 v1 = Hv[(size_t)s1 * 32 + lane];
            f32x4 v2 = Hv[(size_t)s2 * 32 + lane];
            f32x4 v3 = Hv[(size_t)s3 * 32 + lane];
            acc += (v0 + v1) + (v2 + v3);
        }
        for (; j < n; ++j) {
            int s0 = __shfl(eidx, j, 32);
            acc += Hv[(size_t)s0 * 32 + lane];
        }
    }

    f32x4 b = ((const f32x4*)bias)[lane];
    f32x4 r = acc * di + b;
    if (RELU) {
        r.x = fmaxf(r.x, 0.f);
        r.y = fmaxf(r.y, 0.f);
        r.z = fmaxf(r.z, 0.f);
        r.w = fmaxf(r.w, 0.f);
    }
    __builtin_nontemporal_store(r, (f32x4*)OUT + (size_t)node * 32 + lane);
}

// ---------- launch ----------

extern "C" void kernel_launch(void* const* d_in, const int* in_sizes, int n_in,
                              void* d_out, int out_size, void* d_ws, size_t ws_size,
                              hipStream_t stream) {
    const float* x  = (const float*)d_in[0];
    const int*   ei = (const int*)d_in[1];
    const float* W1 = (const float*)d_in[2];
    const float* b1 = (const float*)d_in[3];
    const float* W2 = (const float*)d_in[4];
    const float* b2 = (const float*)d_in[5];
    float* out = (float*)d_out;

    // ws layout (elements, 4B each; chunks padded to keep 16B alignment)
    int*   cnt       = (int*)d_ws;               // 50000
    int*   chunkscan = cnt + 50048;              // 50000
    int*   csum      = chunkscan + 50048;        // 256
    int*   rowptr    = csum + 256;               // 50001
    int*   cursor    = rowptr + 50048;           // 50000
    float* dinv      = (float*)(cursor + 50048); // 50000
    int*   esrc      = (int*)(dinv + 50048);     // 800000
    float* h         = (float*)(esrc + 800000);  // 6,400,000
    float* agg       = h + 6400000;              // 6,400,000

    const int TB = 256;
    const int gbN = (N_NODES + TB - 1) / TB;     // 196
    const int gbE = (N_EDGES + TB - 1) / TB;     // 3125
    const int gbG = (N_NODES + 63) / 64;         // 782 gemm blocks

    // graph build (shared by both layers)
    k_zero<<<gbN, TB, 0, stream>>>(cnt, N_NODES);
    k_hist<<<gbE, TB, 0, stream>>>(ei, cnt);
    k_scan1<<<NCHUNK, TB, 0, stream>>>(cnt, chunkscan, csum);
    k_scan2<<<1, TB, 0, stream>>>(csum, NCHUNK);
    k_finalize<<<gbN, TB, 0, stream>>>(cnt, chunkscan, csum, rowptr, cursor, dinv);
    k_scatter<<<gbE, TB, 0, stream>>>(ei, cursor, esrc);

    // layer 1
    k_gemm<<<gbG, TB, 0, stream>>>(x, W1, dinv, h);
    k_agg<1><<<N_NODES / 8, TB, 0, stream>>>(h, esrc, rowptr, dinv, b1, agg);
    // layer 2
    k_gemm<<<gbG, TB, 0, stream>>>(agg, W2, dinv, h);
    k_agg<0><<<N_NODES / 8, TB, 0, stream>>>(h, esrc, rowptr, dinv, b2, out);
}